// Round 1
// baseline (2238.994 us; speedup 1.0000x reference)
//
#include <hip/hip_runtime.h>

#define R_ 3
#define N_ 50000
#define E_ 800000
#define DIN 128
#define DOUT 64

// ---------------------------------------------------------------------------
// K1: support[r] = X[r] @ W[r]   (fp32 vector GEMM, M=50000, K=128, N=64)
// Block = 256 threads = 4 waves; each block owns 256 rows, each LANE owns one
// row and all 64 output cols (acc[64] in VGPRs). X tile staged TRANSPOSED in
// LDS (x_s[k][row], row-stride 258 -> conflict-free lane-consecutive reads).
// W rows are wave-uniform -> compiler emits scalar s_loads (constant cache),
// so the inner loop is ~64 v_fmac per 1 ds_read.
// ---------------------------------------------------------------------------
__global__ __launch_bounds__(256) void gemm_kernel(const float* __restrict__ X,
                                                   const float* __restrict__ W,
                                                   float* __restrict__ support) {
  const int r = blockIdx.y;
  const int base = blockIdx.x * 256;
  const int t = threadIdx.x;

  __shared__ float x_s[32 * 258];

  const float* Xr = X + (size_t)r * N_ * DIN;
  const float* Wr = W + (size_t)r * DIN * DOUT;

  float acc[DOUT];
#pragma unroll
  for (int o = 0; o < DOUT; ++o) acc[o] = 0.f;

  for (int k0 = 0; k0 < DIN; k0 += 32) {
    __syncthreads();
    // stage 256 rows x 32 k, transposed: x_s[k][row]
#pragma unroll
    for (int i = 0; i < 8; ++i) {
      int rl = i * 32 + (t >> 3);
      int k4 = (t & 7) * 4;
      int rg = base + rl;
      if (rg > N_ - 1) rg = N_ - 1;  // clamp loads; stores are guarded
      const float4 v = *(const float4*)(Xr + (size_t)rg * DIN + k0 + k4);
      x_s[(k4 + 0) * 258 + rl] = v.x;
      x_s[(k4 + 1) * 258 + rl] = v.y;
      x_s[(k4 + 2) * 258 + rl] = v.z;
      x_s[(k4 + 3) * 258 + rl] = v.w;
    }
    __syncthreads();
#pragma unroll 4
    for (int kk = 0; kk < 32; ++kk) {
      const float xv = x_s[kk * 258 + t];
      const float* wrow = Wr + (size_t)(k0 + kk) * DOUT;  // wave-uniform -> s_load
#pragma unroll
      for (int o = 0; o < DOUT; ++o) acc[o] = fmaf(wrow[o], xv, acc[o]);
    }
  }

  const int row = base + t;
  if (row < N_) {
    float* op = support + ((size_t)r * N_ + row) * DOUT;
#pragma unroll
    for (int o = 0; o < DOUT; o += 4) {
      float4 v = {acc[o], acc[o + 1], acc[o + 2], acc[o + 3]};
      *(float4*)(op + o) = v;
    }
  }
}

// ---------------------------------------------------------------------------
// K2: out[r][n][:] = biases[r][:]   (scatter target init; ws is poisoned)
// ---------------------------------------------------------------------------
__global__ __launch_bounds__(256) void init_out(const float* __restrict__ biases,
                                                float* __restrict__ out) {
  const size_t idx = (size_t)blockIdx.x * 256 + threadIdx.x;  // float4 index
  const int o4 = (int)(idx & 15);
  const size_t rn = idx >> 4;  // r*N + n
  const int r = (int)(rn / N_);
  const float4 b = *(const float4*)(biases + r * DOUT + o4 * 4);
  ((float4*)out)[idx] = b;
}

// ---------------------------------------------------------------------------
// K3: COO scatter-SpMM: out[r][rows[e]] += vals[e] * support[r][cols[e]]
// 16 lanes per edge, float4 per lane (256B coalesced gather), native fp32
// atomics via unsafeAtomicAdd (no CAS loop).
// ---------------------------------------------------------------------------
__global__ __launch_bounds__(256) void spmm_kernel(const int* __restrict__ rows,
                                                   const int* __restrict__ cols,
                                                   const float* __restrict__ vals,
                                                   const float* __restrict__ support,
                                                   float* __restrict__ out) {
  const int r = blockIdx.y;
  const int gt = blockIdx.x * 256 + threadIdx.x;
  const int e = gt >> 4;
  const int sub = (threadIdx.x & 15) * 4;
  const size_t eb = (size_t)r * E_ + e;
  const int row = rows[eb];
  const int col = cols[eb];
  const float val = vals[eb];
  const float4 sv = *(const float4*)(support + ((size_t)r * N_ + col) * DOUT + sub);
  float* op = out + ((size_t)r * N_ + row) * DOUT + sub;
  unsafeAtomicAdd(op + 0, val * sv.x);
  unsafeAtomicAdd(op + 1, val * sv.y);
  unsafeAtomicAdd(op + 2, val * sv.z);
  unsafeAtomicAdd(op + 3, val * sv.w);
}

// ---------------------------------------------------------------------------
// K4: scores -> softmax over relations -> weighted sum + w.T output.
// One wave per node; lane = output channel (DOUT==64==wavefront).
// ---------------------------------------------------------------------------
__global__ __launch_bounds__(256) void attn_kernel(const float* __restrict__ out,
                                                   const float* __restrict__ att_w,
                                                   const float* __restrict__ att_b,
                                                   float* __restrict__ dst) {
  const int node = blockIdx.x * 4 + (threadIdx.x >> 6);
  const int lane = threadIdx.x & 63;
  if (node >= N_) return;
  const float o0 = out[((size_t)0 * N_ + node) * DOUT + lane];
  const float o1 = out[((size_t)1 * N_ + node) * DOUT + lane];
  const float o2 = out[((size_t)2 * N_ + node) * DOUT + lane];
  const float aw = att_w[lane];
  float s0 = o0 * aw, s1 = o1 * aw, s2 = o2 * aw;
#pragma unroll
  for (int off = 32; off > 0; off >>= 1) {
    s0 += __shfl_xor(s0, off, 64);
    s1 += __shfl_xor(s1, off, 64);
    s2 += __shfl_xor(s2, off, 64);
  }
  const float ab = att_b[0];
  s0 += ab; s1 += ab; s2 += ab;
  const float m = fmaxf(s0, fmaxf(s1, s2));
  const float e0 = expf(s0 - m), e1 = expf(s1 - m), e2 = expf(s2 - m);
  const float inv = 1.f / (e0 + e1 + e2);
  const float w0 = e0 * inv, w1 = e1 * inv, w2 = e2 * inv;
  dst[(size_t)node * DOUT + lane] = w0 * o0 + w1 * o1 + w2 * o2;
  if (lane < 3) {
    const float w = (lane == 0) ? w0 : ((lane == 1) ? w1 : w2);
    dst[(size_t)N_ * DOUT + (size_t)node * 3 + lane] = w;
  }
}

extern "C" void kernel_launch(void* const* d_in, const int* in_sizes, int n_in,
                              void* d_out, int out_size, void* d_ws, size_t ws_size,
                              hipStream_t stream) {
  const int* adj_rows  = (const int*)d_in[0];
  const int* adj_cols  = (const int*)d_in[1];
  const float* adj_vals = (const float*)d_in[2];
  const float* X       = (const float*)d_in[3];
  const float* W       = (const float*)d_in[4];
  const float* biases  = (const float*)d_in[5];
  const float* att_w   = (const float*)d_in[6];
  const float* att_b   = (const float*)d_in[7];

  float* support = (float*)d_ws;                       // R*N*DOUT = 9.6M floats
  float* out     = support + (size_t)R_ * N_ * DOUT;   // R*N*DOUT = 9.6M floats

  dim3 gg((N_ + 255) / 256, R_);
  gemm_kernel<<<gg, 256, 0, stream>>>(X, W, support);

  init_out<<<(R_ * N_ * DOUT / 4) / 256, 256, 0, stream>>>(biases, out);

  dim3 gs((E_ * 16) / 256, R_);
  spmm_kernel<<<gs, 256, 0, stream>>>(adj_rows, adj_cols, adj_vals, support, out);

  attn_kernel<<<(N_ + 3) / 4, 256, 0, stream>>>(out, att_w, att_b, (float*)d_out);
}

// Round 4
// 694.055 us; speedup vs baseline: 3.2260x; 3.2260x over previous
//
#include <hip/hip_runtime.h>

#define R_ 3
#define N_ 50000
#define E_ 800000
#define DIN 128
#define DOUT 64
#define RT (R_ * N_)          // 150000 output rows total
#define SCAN_NB ((RT + 1023) / 1024)  // 147 scan blocks

// ---------------------------------------------------------------------------
// K1: support[r] = X[r] @ W[r]   (fp32 vector GEMM, M=50000, K=128, N=64)
// ---------------------------------------------------------------------------
__global__ __launch_bounds__(256) void gemm_kernel(const float* __restrict__ X,
                                                   const float* __restrict__ W,
                                                   float* __restrict__ support) {
  const int r = blockIdx.y;
  const int base = blockIdx.x * 256;
  const int t = threadIdx.x;

  __shared__ float x_s[32 * 258];

  const float* Xr = X + (size_t)r * N_ * DIN;
  const float* Wr = W + (size_t)r * DIN * DOUT;

  float acc[DOUT];
#pragma unroll
  for (int o = 0; o < DOUT; ++o) acc[o] = 0.f;

  for (int k0 = 0; k0 < DIN; k0 += 32) {
    __syncthreads();
#pragma unroll
    for (int i = 0; i < 8; ++i) {
      int rl = i * 32 + (t >> 3);
      int k4 = (t & 7) * 4;
      int rg = base + rl;
      if (rg > N_ - 1) rg = N_ - 1;
      const float4 v = *(const float4*)(Xr + (size_t)rg * DIN + k0 + k4);
      x_s[(k4 + 0) * 258 + rl] = v.x;
      x_s[(k4 + 1) * 258 + rl] = v.y;
      x_s[(k4 + 2) * 258 + rl] = v.z;
      x_s[(k4 + 3) * 258 + rl] = v.w;
    }
    __syncthreads();
#pragma unroll 4
    for (int kk = 0; kk < 32; ++kk) {
      const float xv = x_s[kk * 258 + t];
      const float* wrow = Wr + (size_t)(k0 + kk) * DOUT;  // wave-uniform -> s_load
#pragma unroll
      for (int o = 0; o < DOUT; ++o) acc[o] = fmaf(wrow[o], xv, acc[o]);
    }
  }

  const int row = base + t;
  if (row < N_) {
    float* op = support + ((size_t)r * N_ + row) * DOUT;
#pragma unroll
    for (int o = 0; o < DOUT; o += 4) {
      float4 v = {acc[o], acc[o + 1], acc[o + 2], acc[o + 3]};
      *(float4*)(op + o) = v;
    }
  }
}

// ---------------------------------------------------------------------------
// K2: histogram of destination rows: cnt[r*N + rows[e]]++
// ---------------------------------------------------------------------------
__global__ __launch_bounds__(256) void hist_kernel(const int* __restrict__ rows,
                                                   int* __restrict__ cnt) {
  const int r = blockIdx.y;
  const int e = blockIdx.x * 256 + threadIdx.x;
  atomicAdd(&cnt[r * N_ + rows[(size_t)r * E_ + e]], 1);
}

// ---------------------------------------------------------------------------
// K3a: per-block (1024-elem) exclusive scan of cnt -> part, block sums -> bsum
// ---------------------------------------------------------------------------
__global__ __launch_bounds__(256) void scanA(const int* __restrict__ cnt,
                                             int* __restrict__ part,
                                             int* __restrict__ bsum) {
  __shared__ int s[256];
  const int t = threadIdx.x;
  const int base = blockIdx.x * 1024 + t * 4;
  int v0 = 0, v1 = 0, v2 = 0, v3 = 0;
  if (base + 3 < RT) {
    const int4 c = *(const int4*)(cnt + base);
    v0 = c.x; v1 = c.y; v2 = c.z; v3 = c.w;
  } else {
    if (base + 0 < RT) v0 = cnt[base + 0];
    if (base + 1 < RT) v1 = cnt[base + 1];
    if (base + 2 < RT) v2 = cnt[base + 2];
  }
  const int tsum = v0 + v1 + v2 + v3;
  s[t] = tsum;
  __syncthreads();
  for (int off = 1; off < 256; off <<= 1) {
    const int x = s[t];
    const int y = (t >= off) ? s[t - off] : 0;
    __syncthreads();
    s[t] = x + y;
    __syncthreads();
  }
  if (t == 255) bsum[blockIdx.x] = s[255];
  const int e0 = s[t] - tsum;
  const int e1 = e0 + v0, e2 = e1 + v1, e3 = e2 + v2;
  if (base + 3 < RT) {
    *(int4*)(part + base) = make_int4(e0, e1, e2, e3);
  } else {
    if (base + 0 < RT) part[base + 0] = e0;
    if (base + 1 < RT) part[base + 1] = e1;
    if (base + 2 < RT) part[base + 2] = e2;
  }
}

// ---------------------------------------------------------------------------
// K3b: exclusive scan of the 147 block sums (single block, nb <= 256)
// ---------------------------------------------------------------------------
__global__ __launch_bounds__(256) void scanB(int* __restrict__ bsum, int nb) {
  __shared__ int s[256];
  const int t = threadIdx.x;
  const int v = (t < nb) ? bsum[t] : 0;
  s[t] = v;
  __syncthreads();
  for (int off = 1; off < 256; off <<= 1) {
    const int x = s[t];
    const int y = (t >= off) ? s[t - off] : 0;
    __syncthreads();
    s[t] = x + y;
    __syncthreads();
  }
  if (t < nb) bsum[t] = s[t] - v;  // exclusive
}

// ---------------------------------------------------------------------------
// K3c: cursor[i] = part[i] + bsum[i>>10]   (global exclusive row offsets)
// ---------------------------------------------------------------------------
__global__ __launch_bounds__(256) void scanC(const int* __restrict__ part,
                                             const int* __restrict__ bsum,
                                             int* __restrict__ cursor) {
  const int i = blockIdx.x * 256 + threadIdx.x;
  if (i < RT) cursor[i] = part[i] + bsum[i >> 10];
}

// ---------------------------------------------------------------------------
// K4: scatter edges into row-grouped order: edges[pos] = {col, val}
// ---------------------------------------------------------------------------
__global__ __launch_bounds__(256) void scatter_kernel(const int* __restrict__ rows,
                                                      const int* __restrict__ cols,
                                                      const float* __restrict__ vals,
                                                      int* __restrict__ cursor,
                                                      int2* __restrict__ edges) {
  const int r = blockIdx.y;
  const int e = blockIdx.x * 256 + threadIdx.x;
  const size_t eb = (size_t)r * E_ + e;
  const int row = rows[eb];
  const int pos = atomicAdd(&cursor[r * N_ + row], 1);
  edges[pos] = make_int2(cols[eb], __float_as_int(vals[eb]));
}

// ---------------------------------------------------------------------------
// K5: wave-per-row gather: out[rn][lane] = bias + sum_e val*support[col][lane]
// After scatter, cursor[rn] == row_end; begin = end - cnt[rn]. Zero atomics.
// ---------------------------------------------------------------------------
__global__ __launch_bounds__(256) void gather_kernel(const int2* __restrict__ edges,
                                                     const int* __restrict__ cursor,
                                                     const int* __restrict__ cnt,
                                                     const float* __restrict__ support,
                                                     const float* __restrict__ biases,
                                                     float* __restrict__ out) {
  const int rn = blockIdx.x * 4 + (threadIdx.x >> 6);
  if (rn >= RT) return;
  const int lane = threadIdx.x & 63;
  const int r = rn / N_;
  const int end = cursor[rn];
  const int beg = end - cnt[rn];
  const float* sup = support + (size_t)r * N_ * DOUT;
  float acc = biases[r * DOUT + lane];
  for (int e = beg; e < end; ++e) {
    const int2 ed = edges[e];
    acc = fmaf(__int_as_float(ed.y), sup[((size_t)(unsigned)ed.x << 6) + lane], acc);
  }
  out[(size_t)rn * DOUT + lane] = acc;
}

// ---------------------------------------------------------------------------
// K6: softmax over relations + weighted sum
// ---------------------------------------------------------------------------
__global__ __launch_bounds__(256) void attn_kernel(const float* __restrict__ out,
                                                   const float* __restrict__ att_w,
                                                   const float* __restrict__ att_b,
                                                   float* __restrict__ dst) {
  const int node = blockIdx.x * 4 + (threadIdx.x >> 6);
  const int lane = threadIdx.x & 63;
  if (node >= N_) return;
  const float o0 = out[((size_t)0 * N_ + node) * DOUT + lane];
  const float o1 = out[((size_t)1 * N_ + node) * DOUT + lane];
  const float o2 = out[((size_t)2 * N_ + node) * DOUT + lane];
  const float aw = att_w[lane];
  float s0 = o0 * aw, s1 = o1 * aw, s2 = o2 * aw;
#pragma unroll
  for (int off = 32; off > 0; off >>= 1) {
    s0 += __shfl_xor(s0, off, 64);
    s1 += __shfl_xor(s1, off, 64);
    s2 += __shfl_xor(s2, off, 64);
  }
  const float ab = att_b[0];
  s0 += ab; s1 += ab; s2 += ab;
  const float m = fmaxf(s0, fmaxf(s1, s2));
  const float e0 = expf(s0 - m), e1 = expf(s1 - m), e2 = expf(s2 - m);
  const float inv = 1.f / (e0 + e1 + e2);
  const float w0 = e0 * inv, w1 = e1 * inv, w2 = e2 * inv;
  dst[(size_t)node * DOUT + lane] = w0 * o0 + w1 * o1 + w2 * o2;
  if (lane < 3) {
    const float w = (lane == 0) ? w0 : ((lane == 1) ? w1 : w2);
    dst[(size_t)N_ * DOUT + (size_t)node * 3 + lane] = w;
  }
}

extern "C" void kernel_launch(void* const* d_in, const int* in_sizes, int n_in,
                              void* d_out, int out_size, void* d_ws, size_t ws_size,
                              hipStream_t stream) {
  const int* adj_rows   = (const int*)d_in[0];
  const int* adj_cols   = (const int*)d_in[1];
  const float* adj_vals = (const float*)d_in[2];
  const float* X        = (const float*)d_in[3];
  const float* W        = (const float*)d_in[4];
  const float* biases   = (const float*)d_in[5];
  const float* att_w    = (const float*)d_in[6];
  const float* att_b    = (const float*)d_in[7];

  // workspace layout (all 16B-aligned)
  char* p = (char*)d_ws;
  float* support = (float*)p;            p += (size_t)R_ * N_ * DOUT * 4;  // 38.4 MB
  float* out     = (float*)p;            p += (size_t)R_ * N_ * DOUT * 4;  // 38.4 MB
  int2*  edges   = (int2*)p;             p += (size_t)R_ * E_ * 8;         // 19.2 MB
  int*   cnt     = (int*)p;              p += RT * 4;
  int*   part    = (int*)p;              p += RT * 4;
  int*   cursor  = (int*)p;              p += RT * 4;
  int*   bsum    = (int*)p;              p += 1024;

  hipMemsetAsync(cnt, 0, RT * sizeof(int), stream);

  dim3 ge(E_ / 256, R_);
  hist_kernel<<<ge, 256, 0, stream>>>(adj_rows, cnt);
  scanA<<<SCAN_NB, 256, 0, stream>>>(cnt, part, bsum);
  scanB<<<1, 256, 0, stream>>>(bsum, SCAN_NB);
  scanC<<<(RT + 255) / 256, 256, 0, stream>>>(part, bsum, cursor);
  scatter_kernel<<<ge, 256, 0, stream>>>(adj_rows, adj_cols, adj_vals, cursor, edges);

  dim3 gg((N_ + 255) / 256, R_);
  gemm_kernel<<<gg, 256, 0, stream>>>(X, W, support);

  gather_kernel<<<(RT + 3) / 4, 256, 0, stream>>>(edges, cursor, cnt, support, biases, out);

  attn_kernel<<<(N_ + 3) / 4, 256, 0, stream>>>(out, att_w, att_b, (float*)d_out);
}

// Round 9
// 597.111 us; speedup vs baseline: 3.7497x; 1.1624x over previous
//
#include <hip/hip_runtime.h>

#define R_ 3
#define N_ 50000
#define E_ 800000
#define DIN 128
#define DOUT 64
#define RT (R_ * N_)          // 150000 output rows total
#define SCAN_NB ((RT + 1023) / 1024)  // 147 scan blocks

// ---------------------------------------------------------------------------
// K1: support[r] = X[r] @ W[r]   (fp32 vector GEMM, M=50000, K=128, N=64)
// ---------------------------------------------------------------------------
__global__ __launch_bounds__(256) void gemm_kernel(const float* __restrict__ X,
                                                   const float* __restrict__ W,
                                                   float* __restrict__ support) {
  const int r = blockIdx.y;
  const int base = blockIdx.x * 256;
  const int t = threadIdx.x;

  __shared__ float x_s[32 * 258];

  const float* Xr = X + (size_t)r * N_ * DIN;
  const float* Wr = W + (size_t)r * DIN * DOUT;

  float acc[DOUT];
#pragma unroll
  for (int o = 0; o < DOUT; ++o) acc[o] = 0.f;

  for (int k0 = 0; k0 < DIN; k0 += 32) {
    __syncthreads();
#pragma unroll
    for (int i = 0; i < 8; ++i) {
      int rl = i * 32 + (t >> 3);
      int k4 = (t & 7) * 4;
      int rg = base + rl;
      if (rg > N_ - 1) rg = N_ - 1;
      const float4 v = *(const float4*)(Xr + (size_t)rg * DIN + k0 + k4);
      x_s[(k4 + 0) * 258 + rl] = v.x;
      x_s[(k4 + 1) * 258 + rl] = v.y;
      x_s[(k4 + 2) * 258 + rl] = v.z;
      x_s[(k4 + 3) * 258 + rl] = v.w;
    }
    __syncthreads();
#pragma unroll 4
    for (int kk = 0; kk < 32; ++kk) {
      const float xv = x_s[kk * 258 + t];
      const float* wrow = Wr + (size_t)(k0 + kk) * DOUT;  // wave-uniform -> s_load
#pragma unroll
      for (int o = 0; o < DOUT; ++o) acc[o] = fmaf(wrow[o], xv, acc[o]);
    }
  }

  const int row = base + t;
  if (row < N_) {
    float* op = support + ((size_t)r * N_ + row) * DOUT;
#pragma unroll
    for (int o = 0; o < DOUT; o += 4) {
      float4 v = {acc[o], acc[o + 1], acc[o + 2], acc[o + 3]};
      *(float4*)(op + o) = v;
    }
  }
}

// ---------------------------------------------------------------------------
// K2: histogram of destination rows: cnt[r*N + rows[e]]++
// ---------------------------------------------------------------------------
__global__ __launch_bounds__(256) void hist_kernel(const int* __restrict__ rows,
                                                   int* __restrict__ cnt) {
  const int r = blockIdx.y;
  const int e = blockIdx.x * 256 + threadIdx.x;
  atomicAdd(&cnt[r * N_ + rows[(size_t)r * E_ + e]], 1);
}

// ---------------------------------------------------------------------------
// K3a: per-block (1024-elem) exclusive scan of cnt -> part, block sums -> bsum
// ---------------------------------------------------------------------------
__global__ __launch_bounds__(256) void scanA(const int* __restrict__ cnt,
                                             int* __restrict__ part,
                                             int* __restrict__ bsum) {
  __shared__ int s[256];
  const int t = threadIdx.x;
  const int base = blockIdx.x * 1024 + t * 4;
  int v0 = 0, v1 = 0, v2 = 0, v3 = 0;
  if (base + 3 < RT) {
    const int4 c = *(const int4*)(cnt + base);
    v0 = c.x; v1 = c.y; v2 = c.z; v3 = c.w;
  } else {
    if (base + 0 < RT) v0 = cnt[base + 0];
    if (base + 1 < RT) v1 = cnt[base + 1];
    if (base + 2 < RT) v2 = cnt[base + 2];
  }
  const int tsum = v0 + v1 + v2 + v3;
  s[t] = tsum;
  __syncthreads();
  for (int off = 1; off < 256; off <<= 1) {
    const int x = s[t];
    const int y = (t >= off) ? s[t - off] : 0;
    __syncthreads();
    s[t] = x + y;
    __syncthreads();
  }
  if (t == 255) bsum[blockIdx.x] = s[255];
  const int e0 = s[t] - tsum;
  const int e1 = e0 + v0, e2 = e1 + v1, e3 = e2 + v2;
  if (base + 3 < RT) {
    *(int4*)(part + base) = make_int4(e0, e1, e2, e3);
  } else {
    if (base + 0 < RT) part[base + 0] = e0;
    if (base + 1 < RT) part[base + 1] = e1;
    if (base + 2 < RT) part[base + 2] = e2;
  }
}

// ---------------------------------------------------------------------------
// K3b: exclusive scan of the 147 block sums (single block, nb <= 256)
// ---------------------------------------------------------------------------
__global__ __launch_bounds__(256) void scanB(int* __restrict__ bsum, int nb) {
  __shared__ int s[256];
  const int t = threadIdx.x;
  const int v = (t < nb) ? bsum[t] : 0;
  s[t] = v;
  __syncthreads();
  for (int off = 1; off < 256; off <<= 1) {
    const int x = s[t];
    const int y = (t >= off) ? s[t - off] : 0;
    __syncthreads();
    s[t] = x + y;
    __syncthreads();
  }
  if (t < nb) bsum[t] = s[t] - v;  // exclusive
}

// ---------------------------------------------------------------------------
// K3c: cursor[i] = part[i] + bsum[i>>10]   (global exclusive row offsets)
// ---------------------------------------------------------------------------
__global__ __launch_bounds__(256) void scanC(const int* __restrict__ part,
                                             const int* __restrict__ bsum,
                                             int* __restrict__ cursor) {
  const int i = blockIdx.x * 256 + threadIdx.x;
  if (i < RT) cursor[i] = part[i] + bsum[i >> 10];
}

// ---------------------------------------------------------------------------
// K4: scatter edges into row-grouped order: edges[pos] = {col, val}
// ---------------------------------------------------------------------------
__global__ __launch_bounds__(256) void scatter_kernel(const int* __restrict__ rows,
                                                      const int* __restrict__ cols,
                                                      const float* __restrict__ vals,
                                                      int* __restrict__ cursor,
                                                      int2* __restrict__ edges) {
  const int r = blockIdx.y;
  const int e = blockIdx.x * 256 + threadIdx.x;
  const size_t eb = (size_t)r * E_ + e;
  const int row = rows[eb];
  const int pos = atomicAdd(&cursor[r * N_ + row], 1);
  edges[pos] = make_int2(cols[eb], __float_as_int(vals[eb]));
}

// ---------------------------------------------------------------------------
// K5: wave-per-row gather, 8-deep software pipeline.
// lane = output channel. Per 8 edges: one 64B wave-uniform edge-record load
// (scalar path), then 8 independent 256B support gathers in flight, then 8
// fmas on 2 alternating accumulators. Latency-hiding was the round-4
// bottleneck (VALUBusy 16%, ~1300 cyc/edge serial chain).
// ---------------------------------------------------------------------------
__global__ __launch_bounds__(256) void gather_kernel(const int2* __restrict__ edges,
                                                     const int* __restrict__ cursor,
                                                     const int* __restrict__ cnt,
                                                     const float* __restrict__ support,
                                                     const float* __restrict__ biases,
                                                     float* __restrict__ out) {
  const int rn = blockIdx.x * 4 + (threadIdx.x >> 6);
  if (rn >= RT) return;
  const int lane = threadIdx.x & 63;
  const int r = rn / N_;
  const int end = cursor[rn];
  int e = end - cnt[rn];
  const float* sup = support + (size_t)r * N_ * DOUT + lane;

  float a0 = biases[r * DOUT + lane];
  float a1 = 0.f;

  for (; e + 8 <= end; e += 8) {
    const int2 d0 = edges[e + 0];
    const int2 d1 = edges[e + 1];
    const int2 d2 = edges[e + 2];
    const int2 d3 = edges[e + 3];
    const int2 d4 = edges[e + 4];
    const int2 d5 = edges[e + 5];
    const int2 d6 = edges[e + 6];
    const int2 d7 = edges[e + 7];
    const float s0 = sup[(size_t)(unsigned)d0.x << 6];
    const float s1 = sup[(size_t)(unsigned)d1.x << 6];
    const float s2 = sup[(size_t)(unsigned)d2.x << 6];
    const float s3 = sup[(size_t)(unsigned)d3.x << 6];
    const float s4 = sup[(size_t)(unsigned)d4.x << 6];
    const float s5 = sup[(size_t)(unsigned)d5.x << 6];
    const float s6 = sup[(size_t)(unsigned)d6.x << 6];
    const float s7 = sup[(size_t)(unsigned)d7.x << 6];
    a0 = fmaf(__int_as_float(d0.y), s0, a0);
    a1 = fmaf(__int_as_float(d1.y), s1, a1);
    a0 = fmaf(__int_as_float(d2.y), s2, a0);
    a1 = fmaf(__int_as_float(d3.y), s3, a1);
    a0 = fmaf(__int_as_float(d4.y), s4, a0);
    a1 = fmaf(__int_as_float(d5.y), s5, a1);
    a0 = fmaf(__int_as_float(d6.y), s6, a0);
    a1 = fmaf(__int_as_float(d7.y), s7, a1);
  }
  for (; e < end; ++e) {
    const int2 ed = edges[e];
    a0 = fmaf(__int_as_float(ed.y), sup[(size_t)(unsigned)ed.x << 6], a0);
  }
  out[(size_t)rn * DOUT + lane] = a0 + a1;
}

// ---------------------------------------------------------------------------
// K6: softmax over relations + weighted sum
// ---------------------------------------------------------------------------
__global__ __launch_bounds__(256) void attn_kernel(const float* __restrict__ out,
                                                   const float* __restrict__ att_w,
                                                   const float* __restrict__ att_b,
                                                   float* __restrict__ dst) {
  const int node = blockIdx.x * 4 + (threadIdx.x >> 6);
  const int lane = threadIdx.x & 63;
  if (node >= N_) return;
  const float o0 = out[((size_t)0 * N_ + node) * DOUT + lane];
  const float o1 = out[((size_t)1 * N_ + node) * DOUT + lane];
  const float o2 = out[((size_t)2 * N_ + node) * DOUT + lane];
  const float aw = att_w[lane];
  float s0 = o0 * aw, s1 = o1 * aw, s2 = o2 * aw;
#pragma unroll
  for (int off = 32; off > 0; off >>= 1) {
    s0 += __shfl_xor(s0, off, 64);
    s1 += __shfl_xor(s1, off, 64);
    s2 += __shfl_xor(s2, off, 64);
  }
  const float ab = att_b[0];
  s0 += ab; s1 += ab; s2 += ab;
  const float m = fmaxf(s0, fmaxf(s1, s2));
  const float e0 = expf(s0 - m), e1 = expf(s1 - m), e2 = expf(s2 - m);
  const float inv = 1.f / (e0 + e1 + e2);
  const float w0 = e0 * inv, w1 = e1 * inv, w2 = e2 * inv;
  dst[(size_t)node * DOUT + lane] = w0 * o0 + w1 * o1 + w2 * o2;
  if (lane < 3) {
    const float w = (lane == 0) ? w0 : ((lane == 1) ? w1 : w2);
    dst[(size_t)N_ * DOUT + (size_t)node * 3 + lane] = w;
  }
}

extern "C" void kernel_launch(void* const* d_in, const int* in_sizes, int n_in,
                              void* d_out, int out_size, void* d_ws, size_t ws_size,
                              hipStream_t stream) {
  const int* adj_rows   = (const int*)d_in[0];
  const int* adj_cols   = (const int*)d_in[1];
  const float* adj_vals = (const float*)d_in[2];
  const float* X        = (const float*)d_in[3];
  const float* W        = (const float*)d_in[4];
  const float* biases   = (const float*)d_in[5];
  const float* att_w    = (const float*)d_in[6];
  const float* att_b    = (const float*)d_in[7];

  // workspace layout (all 16B-aligned)
  char* p = (char*)d_ws;
  float* support = (float*)p;            p += (size_t)R_ * N_ * DOUT * 4;  // 38.4 MB
  float* out     = (float*)p;            p += (size_t)R_ * N_ * DOUT * 4;  // 38.4 MB
  int2*  edges   = (int2*)p;             p += (size_t)R_ * E_ * 8;         // 19.2 MB
  int*   cnt     = (int*)p;              p += RT * 4;
  int*   part    = (int*)p;              p += RT * 4;
  int*   cursor  = (int*)p;              p += RT * 4;
  int*   bsum    = (int*)p;              p += 1024;

  hipMemsetAsync(cnt, 0, RT * sizeof(int), stream);

  dim3 ge(E_ / 256, R_);
  hist_kernel<<<ge, 256, 0, stream>>>(adj_rows, cnt);
  scanA<<<SCAN_NB, 256, 0, stream>>>(cnt, part, bsum);
  scanB<<<1, 256, 0, stream>>>(bsum, SCAN_NB);
  scanC<<<(RT + 255) / 256, 256, 0, stream>>>(part, bsum, cursor);
  scatter_kernel<<<ge, 256, 0, stream>>>(adj_rows, adj_cols, adj_vals, cursor, edges);

  dim3 gg((N_ + 255) / 256, R_);
  gemm_kernel<<<gg, 256, 0, stream>>>(X, W, support);

  gather_kernel<<<(RT + 3) / 4, 256, 0, stream>>>(edges, cursor, cnt, support, biases, out);

  attn_kernel<<<(N_ + 3) / 4, 256, 0, stream>>>(out, att_w, att_b, (float*)d_out);
}